// Round 1
// baseline (288.452 us; speedup 1.0000x reference)
//
#include <hip/hip_runtime.h>
#include <hip/hip_bf16.h>

#define B_ 4
#define T_ 8192
#define D_ 512
#define H_ 512
#define M_ (B_ * T_)            // 32768 rows of x
#define CHUNK_ 128
#define NCHUNK_ (T_ / CHUNK_)   // 64
#define SEQS_ (B_ * H_)         // 2048 independent scan sequences

typedef __attribute__((ext_vector_type(8))) short bf16x8;
typedef __attribute__((ext_vector_type(4))) float f32x4;

__device__ __forceinline__ unsigned short f2bf(float x) {
  union { float f; unsigned int u; } c; c.f = x;
  unsigned int u = c.u;
  unsigned int r = (u + 0x7fffu + ((u >> 16) & 1u)) >> 16;  // RTNE
  return (unsigned short)r;
}
__device__ __forceinline__ float bf2f(unsigned short h) {
  union { unsigned int u; float f; } c; c.u = ((unsigned int)h) << 16;
  return c.f;
}

// ---------------------------------------------------------------------------
// Kernel 1: convert W_f/W_i/W_h (fp32 [D][H]) -> Wt bf16 [3][H][D] (transposed
// so GEMM B-tiles are contiguous along K for ds_read_b128 fragment loads).
// ---------------------------------------------------------------------------
__global__ void wt_convert(const float* __restrict__ Wf, const float* __restrict__ Wi,
                           const float* __restrict__ Wh, unsigned short* __restrict__ Wt) {
  int e = blockIdx.x * 256 + threadIdx.x;   // 3*512*512 = 786432 total
  int g = e >> 18;                          // / (512*512)
  int rem = e & 262143;
  int k = rem >> 9;
  int n = rem & 511;                        // consecutive tid -> consecutive n (coalesced read)
  const float* W = (g == 0) ? Wf : (g == 1) ? Wi : Wh;
  Wt[((size_t)g * H_ + n) * D_ + k] = f2bf(W[k * H_ + n]);
}

// ---------------------------------------------------------------------------
// Kernel 2: fused 3-gate GEMM + gate epilogue.
// C_g = x @ W_g + b_g for g in {f,i,h}; epilogue computes
//   a = forget gate, v = input_gate * g(h_pre)
// packed as (a | v<<16) bf16 pair per (row, h) into AV.
// Tile: BM=128, BN=64, BK=64; 256 threads = 4 waves, each wave 64x32.
// ---------------------------------------------------------------------------
__global__ __launch_bounds__(256, 3)
void gemm_gates(const float* __restrict__ x, const unsigned short* __restrict__ Wt,
                const float* __restrict__ bF, const float* __restrict__ bI,
                const float* __restrict__ bH, unsigned int* __restrict__ AV) {
  __shared__ unsigned short xs[128][72];      // +8 pad: breaks 16-way bank conflict
  __shared__ unsigned short wsm[3][64][72];

  const int tid = threadIdx.x;
  const int n0 = blockIdx.x * 64;    // 8 n-tiles (x-major so same m-tile is L2-temporal)
  const int m0 = blockIdx.y * 128;   // 256 m-tiles
  const int wave = tid >> 6;
  const int lane = tid & 63;
  const int wm = (wave & 1) * 64;
  const int wn = (wave >> 1) * 32;
  const int l16 = lane & 15;
  const int quad = lane >> 4;

  const int srow = tid >> 4;         // 0..15
  const int scol = (tid & 15) * 4;   // 0..60 step 4

  f32x4 acc[3][4][2];
  #pragma unroll
  for (int g = 0; g < 3; ++g)
    #pragma unroll
    for (int mi = 0; mi < 4; ++mi)
      #pragma unroll
      for (int ni = 0; ni < 2; ++ni)
        acc[g][mi][ni] = (f32x4){0.f, 0.f, 0.f, 0.f};

  #pragma unroll 1
  for (int kb = 0; kb < D_; kb += 64) {
    // stage x tile (fp32 -> bf16), 128x64
    #pragma unroll
    for (int rr = 0; rr < 128; rr += 16) {
      const float4 v = *(const float4*)(x + (size_t)(m0 + rr + srow) * D_ + kb + scol);
      ushort4 hv;
      hv.x = f2bf(v.x); hv.y = f2bf(v.y); hv.z = f2bf(v.z); hv.w = f2bf(v.w);
      *(ushort4*)(&xs[rr + srow][scol]) = hv;
    }
    // stage W tiles (already bf16, [g][n][k] layout), 3 x 64x64
    #pragma unroll
    for (int g = 0; g < 3; ++g) {
      #pragma unroll
      for (int rr = 0; rr < 64; rr += 16) {
        ushort4 wv = *(const ushort4*)(Wt + ((size_t)g * H_ + n0 + rr + srow) * D_ + kb + scol);
        *(ushort4*)(&wsm[g][rr + srow][scol]) = wv;
      }
    }
    __syncthreads();
    #pragma unroll
    for (int kk = 0; kk < 64; kk += 32) {
      bf16x8 af[4];
      #pragma unroll
      for (int mi = 0; mi < 4; ++mi)
        af[mi] = *(const bf16x8*)(&xs[wm + mi * 16 + l16][kk + quad * 8]);
      bf16x8 bfr[3][2];
      #pragma unroll
      for (int g = 0; g < 3; ++g)
        #pragma unroll
        for (int ni = 0; ni < 2; ++ni)
          bfr[g][ni] = *(const bf16x8*)(&wsm[g][wn + ni * 16 + l16][kk + quad * 8]);
      #pragma unroll
      for (int g = 0; g < 3; ++g)
        #pragma unroll
        for (int mi = 0; mi < 4; ++mi)
          #pragma unroll
          for (int ni = 0; ni < 2; ++ni)
            acc[g][mi][ni] = __builtin_amdgcn_mfma_f32_16x16x32_bf16(
                af[mi], bfr[g][ni], acc[g][mi][ni], 0, 0, 0);
    }
    __syncthreads();
  }

  // epilogue: C/D layout col=lane&15, row=quad*4+reg
  #pragma unroll
  for (int ni = 0; ni < 2; ++ni) {
    const int col = n0 + wn + ni * 16 + l16;
    const float bfv = bF[col], biv = bI[col], bhv = bH[col];
    #pragma unroll
    for (int mi = 0; mi < 4; ++mi) {
      const int rowb = m0 + wm + mi * 16 + quad * 4;
      #pragma unroll
      for (int r = 0; r < 4; ++r) {
        float fp = acc[0][mi][ni][r] + bfv;
        float ip = acc[1][mi][ni][r] + biv;
        float hp = acc[2][mi][ni][r] + bhv;
        fp = fminf(fmaxf(fp, -30.f), 30.f);
        ip = fminf(fmaxf(ip, -30.f), 30.f);
        hp = fminf(fmaxf(hp, -30.f), 30.f);
        // f = sigmoid(sp(-i_pre)-sp(-f_pre)) = (1+Ei)/(2+Ef+Ei); i = 1-f
        const float Ef = __expf(-fp);
        const float Ei = __expf(-ip);
        const float rr2 = 1.f / (2.f + Ef + Ei);
        const float fgate = (1.f + Ei) * rr2;
        const float igate = (1.f + Ef) * rr2;
        // g(x) = x+0.5 (x>=0) else sigmoid(x)
        float gval;
        if (hp >= 0.f) gval = hp + 0.5f;
        else gval = 1.f / (1.f + __expf(-hp));
        const float vval = igate * gval;
        AV[(size_t)(rowb + r) * H_ + col] =
            (unsigned int)f2bf(fgate) | ((unsigned int)f2bf(vval) << 16);
      }
    }
  }
}

// ---------------------------------------------------------------------------
// Kernel 3: per-chunk scan. Each thread owns one (b,h) for one 128-step chunk:
// F = prod a_t, S = recurrence with zero init. Coalesced: lane -> h.
// ---------------------------------------------------------------------------
__global__ void scan_pass1(const unsigned int* __restrict__ AV,
                           float* __restrict__ Fc, float* __restrict__ Sc) {
  const int seq = blockIdx.x * 256 + threadIdx.x;  // 0..2047
  const int b = seq >> 9;
  const int h = seq & 511;
  const int c = blockIdx.y;
  const unsigned int* p = AV + ((size_t)(b * T_ + c * CHUNK_) * H_) + h;
  float F = 1.f, S = 0.f;
  #pragma unroll 8
  for (int t = 0; t < CHUNK_; ++t) {
    unsigned int w = p[(size_t)t * H_];
    float a = bf2f((unsigned short)(w & 0xffffu));
    float v = bf2f((unsigned short)(w >> 16));
    F *= a;
    S = fmaf(a, S, v);
  }
  Fc[c * SEQS_ + seq] = F;
  Sc[c * SEQS_ + seq] = S;
}

// ---------------------------------------------------------------------------
// Kernel 4: sequential carry scan over the 64 chunks per sequence.
// Also writes out[:,0,:] = g(h_0).
// ---------------------------------------------------------------------------
__global__ void scan_pass2(const float* __restrict__ h0, const float* __restrict__ Fc,
                           const float* __restrict__ Sc, float* __restrict__ Hin,
                           float* __restrict__ out) {
  const int seq = blockIdx.x * 256 + threadIdx.x;  // 2048 threads total
  const int b = seq >> 9;
  const int h = seq & 511;
  float x = h0[seq];
  float hcur = (x >= 0.f) ? (x + 0.5f) : (1.f / (1.f + __expf(-x)));
  out[(size_t)(b * (T_ + 1)) * H_ + h] = hcur;
  #pragma unroll 8
  for (int c = 0; c < NCHUNK_; ++c) {
    Hin[c * SEQS_ + seq] = hcur;
    hcur = fmaf(Fc[c * SEQS_ + seq], hcur, Sc[c * SEQS_ + seq]);
  }
}

// ---------------------------------------------------------------------------
// Kernel 5: fix-up pass — rerun chunk recurrence with the carried h_in,
// writing out[:,1:,:].
// ---------------------------------------------------------------------------
__global__ void scan_pass3(const unsigned int* __restrict__ AV,
                           const float* __restrict__ Hin, float* __restrict__ out) {
  const int seq = blockIdx.x * 256 + threadIdx.x;
  const int b = seq >> 9;
  const int h = seq & 511;
  const int c = blockIdx.y;
  const unsigned int* p = AV + ((size_t)(b * T_ + c * CHUNK_) * H_) + h;
  float* o = out + ((size_t)(b * (T_ + 1) + c * CHUNK_ + 1) * H_) + h;
  float hcur = Hin[c * SEQS_ + seq];
  #pragma unroll 8
  for (int t = 0; t < CHUNK_; ++t) {
    unsigned int w = p[(size_t)t * H_];
    float a = bf2f((unsigned short)(w & 0xffffu));
    float v = bf2f((unsigned short)(w >> 16));
    hcur = fmaf(a, hcur, v);
    o[(size_t)t * H_] = hcur;
  }
}

extern "C" void kernel_launch(void* const* d_in, const int* in_sizes, int n_in,
                              void* d_out, int out_size, void* d_ws, size_t ws_size,
                              hipStream_t stream) {
  const float* x  = (const float*)d_in[0];
  const float* h0 = (const float*)d_in[1];
  const float* Wf = (const float*)d_in[2];
  const float* bF = (const float*)d_in[3];
  const float* Wi = (const float*)d_in[4];
  const float* bI = (const float*)d_in[5];
  const float* Wh = (const float*)d_in[6];
  const float* bH = (const float*)d_in[7];
  float* out = (float*)d_out;

  char* ws = (char*)d_ws;
  size_t off = 0;
  unsigned int* AV = (unsigned int*)(ws + off);  off += (size_t)M_ * H_ * 4;        // 64 MB
  unsigned short* Wt = (unsigned short*)(ws + off); off += (size_t)3 * H_ * D_ * 2; // 1.5 MB
  float* Fc  = (float*)(ws + off); off += (size_t)NCHUNK_ * SEQS_ * 4;              // 512 KB
  float* Sc  = (float*)(ws + off); off += (size_t)NCHUNK_ * SEQS_ * 4;              // 512 KB
  float* Hin = (float*)(ws + off); off += (size_t)NCHUNK_ * SEQS_ * 4;              // 512 KB

  wt_convert<<<(3 * H_ * D_) / 256, 256, 0, stream>>>(Wf, Wi, Wh, Wt);
  gemm_gates<<<dim3(H_ / 64, M_ / 128), 256, 0, stream>>>(x, Wt, bF, bI, bH, AV);
  scan_pass1<<<dim3(SEQS_ / 256, NCHUNK_), 256, 0, stream>>>(AV, Fc, Sc);
  scan_pass2<<<SEQS_ / 256, 256, 0, stream>>>(h0, Fc, Sc, Hin, out);
  scan_pass3<<<dim3(SEQS_ / 256, NCHUNK_), 256, 0, stream>>>(AV, Hin, out);
}

// Round 2
// 248.296 us; speedup vs baseline: 1.1617x; 1.1617x over previous
//
#include <hip/hip_runtime.h>
#include <hip/hip_bf16.h>

#define B_ 4
#define T_ 8192
#define D_ 512
#define H_ 512
#define M_ (B_ * T_)            // 32768 rows of x
#define CHUNK_ 128
#define NCHUNK_ (T_ / CHUNK_)   // 64
#define SEQS_ (B_ * H_)         // 2048 independent scan sequences

typedef __attribute__((ext_vector_type(8))) short bf16x8;
typedef __attribute__((ext_vector_type(4))) float f32x4;

__device__ __forceinline__ unsigned short f2bf(float x) {
  union { float f; unsigned int u; } c; c.f = x;
  unsigned int u = c.u;
  unsigned int r = (u + 0x7fffu + ((u >> 16) & 1u)) >> 16;  // RTNE
  return (unsigned short)r;
}
__device__ __forceinline__ float bf2f(unsigned short h) {
  union { unsigned int u; float f; } c; c.u = ((unsigned int)h) << 16;
  return c.f;
}

// async 16B/lane global->LDS: lds dest is wave-uniform base, HW adds lane*16
__device__ __forceinline__ void gll16(const void* g, void* l) {
  __builtin_amdgcn_global_load_lds(
      (const __attribute__((address_space(1))) unsigned int*)g,
      (__attribute__((address_space(3))) unsigned int*)l, 16, 0, 0);
}

// ---------------------------------------------------------------------------
// Kernel 1: W_f/W_i/W_h fp32 [D][H] -> Wt bf16 [3][H][D] (K-contiguous rows).
// ---------------------------------------------------------------------------
__global__ void wt_convert(const float* __restrict__ Wf, const float* __restrict__ Wi,
                           const float* __restrict__ Wh, unsigned short* __restrict__ Wt) {
  int e = blockIdx.x * 256 + threadIdx.x;   // 786432 total
  int g = e >> 18;
  int rem = e & 262143;
  int k = rem >> 9;
  int n = rem & 511;
  const float* W = (g == 0) ? Wf : (g == 1) ? Wi : Wh;
  Wt[((size_t)g * H_ + n) * D_ + k] = f2bf(W[k * H_ + n]);
}

// ---------------------------------------------------------------------------
// Kernel 2: x fp32 -> bf16 (so GEMM staging can use global_load_lds directly).
// ---------------------------------------------------------------------------
__global__ void x_convert(const float* __restrict__ x, unsigned short* __restrict__ xb) {
  size_t i = ((size_t)blockIdx.x * 256 + threadIdx.x) * 8;
  float4 a = *(const float4*)(x + i);
  float4 b = *(const float4*)(x + i + 4);
  ushort4 ha; ha.x = f2bf(a.x); ha.y = f2bf(a.y); ha.z = f2bf(a.z); ha.w = f2bf(a.w);
  ushort4 hb; hb.x = f2bf(b.x); hb.y = f2bf(b.y); hb.z = f2bf(b.z); hb.w = f2bf(b.w);
  *(ushort4*)(xb + i) = ha;
  *(ushort4*)(xb + i + 4) = hb;
}

// ---------------------------------------------------------------------------
// Kernel 3: fused 3-gate GEMM + gate epilogue.
// BM=128(=CHUNK), BN=64, BK=64; 256 threads = 4 waves, wave tile 64x32 (x3 gates).
// LDS: unpadded, XOR-swizzled (16B chunk index ^= row&7) so global_load_lds's
// lane-linear writes coexist with 2-way-max-conflict ds_read_b128 frag reads.
// AV output in chunk-blocked layout: [b*64+c][8 hb][128 t][64 hl] (uint pairs).
// ---------------------------------------------------------------------------
__global__ __launch_bounds__(256, 2)
void gemm_gates(const unsigned short* __restrict__ xb, const unsigned short* __restrict__ Wt,
                const float* __restrict__ bF, const float* __restrict__ bI,
                const float* __restrict__ bH, unsigned int* __restrict__ AV) {
  __shared__ unsigned short xs[128 * 64];     // 16 KB
  __shared__ unsigned short wsm[3 * 64 * 64]; // 24 KB

  const int tid = threadIdx.x;
  const int hb = blockIdx.x;          // 0..7  (n-tile)
  const int m0 = blockIdx.y * 128;    // 0..255 (m-tile = one scan chunk)
  const int n0 = hb * 64;
  const int wave = tid >> 6;
  const int lane = tid & 63;
  const int wm = (wave & 1) * 64;
  const int wn = (wave >> 1) * 32;
  const int l16 = lane & 15;
  const int quad = lane >> 4;

  // staging lane geometry: each 1KB instr covers 8 rows x 128B; lane -> (row, chunk)
  const int lrow = lane >> 3;                 // 0..7
  const int lch = (lane & 7) ^ lrow;          // swizzled source 16B-chunk

  // per-lane global element offsets (add kb each iter)
  int xoff[4];
  #pragma unroll
  for (int j = 0; j < 4; ++j) {
    const int gx = wave * 4 + j;              // 0..15 : rows gx*8..gx*8+7
    xoff[j] = (m0 + gx * 8 + lrow) * D_ + lch * 8;
  }
  int woff[6], wdst[6];
  #pragma unroll
  for (int q = 0; q < 6; ++q) {
    const int gw = wave * 6 + q;              // 0..23
    const int g = gw >> 3, rg = gw & 7;
    woff[q] = (g * H_ + n0 + rg * 8 + lrow) * D_ + lch * 8;
    wdst[q] = g * 4096 + rg * 512;
  }

  f32x4 acc[3][4][2];
  #pragma unroll
  for (int g = 0; g < 3; ++g)
    #pragma unroll
    for (int mi = 0; mi < 4; ++mi)
      #pragma unroll
      for (int ni = 0; ni < 2; ++ni)
        acc[g][mi][ni] = (f32x4){0.f, 0.f, 0.f, 0.f};

  #pragma unroll 1
  for (int kb = 0; kb < D_; kb += 64) {
    #pragma unroll
    for (int j = 0; j < 4; ++j)
      gll16(xb + xoff[j] + kb, xs + (wave * 4 + j) * 512);
    #pragma unroll
    for (int q = 0; q < 6; ++q)
      gll16(Wt + woff[q] + kb, wsm + wdst[q]);
    __syncthreads();

    #pragma unroll
    for (int kk = 0; kk < 64; kk += 32) {
      const int kc = kk >> 3;                 // base 16B chunk (0 or 4)
      bf16x8 af[4];
      #pragma unroll
      for (int mi = 0; mi < 4; ++mi) {
        const int r = wm + mi * 16 + l16;
        af[mi] = *(const bf16x8*)(xs + r * 64 + ((kc + quad) ^ (r & 7)) * 8);
      }
      bf16x8 bfr[3][2];
      #pragma unroll
      for (int g = 0; g < 3; ++g)
        #pragma unroll
        for (int ni = 0; ni < 2; ++ni) {
          const int r = wn + ni * 16 + l16;
          bfr[g][ni] = *(const bf16x8*)(wsm + g * 4096 + r * 64 + ((kc + quad) ^ (r & 7)) * 8);
        }
      #pragma unroll
      for (int g = 0; g < 3; ++g)
        #pragma unroll
        for (int mi = 0; mi < 4; ++mi)
          #pragma unroll
          for (int ni = 0; ni < 2; ++ni)
            acc[g][mi][ni] = __builtin_amdgcn_mfma_f32_16x16x32_bf16(
                af[mi], bfr[g][ni], acc[g][mi][ni], 0, 0, 0);
    }
    __syncthreads();
  }

  // epilogue: C/D layout col=lane&15, row=quad*4+reg
  const size_t avbase = ((size_t)blockIdx.y * 8 + hb) * (CHUNK_ * 64);
  #pragma unroll
  for (int ni = 0; ni < 2; ++ni) {
    const int col = n0 + wn + ni * 16 + l16;
    const int hl = wn + ni * 16 + l16;
    const float bfv = bF[col], biv = bI[col], bhv = bH[col];
    #pragma unroll
    for (int mi = 0; mi < 4; ++mi) {
      const int tb = wm + mi * 16 + quad * 4;   // t within chunk
      #pragma unroll
      for (int r = 0; r < 4; ++r) {
        float fp = acc[0][mi][ni][r] + bfv;
        float ip = acc[1][mi][ni][r] + biv;
        float hp = acc[2][mi][ni][r] + bhv;
        fp = fminf(fmaxf(fp, -30.f), 30.f);
        ip = fminf(fmaxf(ip, -30.f), 30.f);
        hp = fminf(fmaxf(hp, -30.f), 30.f);
        const float Ef = __expf(-fp);
        const float Ei = __expf(-ip);
        const float rr2 = 1.f / (2.f + Ef + Ei);
        const float fgate = (1.f + Ei) * rr2;   // forget gate
        const float igate = (1.f + Ef) * rr2;   // input gate = 1-f
        float gval;
        if (hp >= 0.f) gval = hp + 0.5f;
        else gval = 1.f / (1.f + __expf(-hp));
        const float vval = igate * gval;
        AV[avbase + (size_t)(tb + r) * 64 + hl] =
            (unsigned int)f2bf(fgate) | ((unsigned int)f2bf(vval) << 16);
      }
    }
  }
}

// ---------------------------------------------------------------------------
// Kernel 4: per-chunk scan. Thread = (b,c,hb,hl); AV reads are wave-sequential
// 256B streams. Writes Fc/Sc transposed [seq][c] for pass2 vector loads.
// ---------------------------------------------------------------------------
__global__ void scan_pass1(const unsigned int* __restrict__ AV,
                           float* __restrict__ Fc, float* __restrict__ Sc) {
  const int gid = blockIdx.x * 256 + threadIdx.x;   // 131072 total
  const int hl = gid & 63;
  const int rest = gid >> 6;                        // (b*64+c)*8 + hb
  const int hbi = rest & 7;
  const int c = (rest >> 3) & 63;
  const int b = rest >> 9;
  const unsigned int* p = AV + (size_t)rest * (CHUNK_ * 64) + hl;
  float F = 1.f, S = 0.f;
  #pragma unroll 8
  for (int t = 0; t < CHUNK_; ++t) {
    unsigned int w = p[t * 64];
    float a = bf2f((unsigned short)(w & 0xffffu));
    float v = bf2f((unsigned short)(w >> 16));
    F *= a;
    S = fmaf(a, S, v);
  }
  const int s = b * 512 + hbi * 64 + hl;            // seq id
  Fc[(size_t)s * NCHUNK_ + c] = F;
  Sc[(size_t)s * NCHUNK_ + c] = S;
}

// ---------------------------------------------------------------------------
// Kernel 5: carry scan over 64 chunks per sequence; writes out[:,0,:].
// ---------------------------------------------------------------------------
__global__ void scan_pass2(const float* __restrict__ h0, const float* __restrict__ Fc,
                           const float* __restrict__ Sc, float* __restrict__ Hin,
                           float* __restrict__ out) {
  const int s = blockIdx.x * 256 + threadIdx.x;     // 0..2047
  const int b = s >> 9;
  const int h = s & 511;
  float x = h0[s];
  float hcur = (x >= 0.f) ? (x + 0.5f) : (1.f / (1.f + __expf(-x)));
  out[(size_t)(b * (T_ + 1)) * H_ + h] = hcur;
  const float4* f4 = (const float4*)(Fc + (size_t)s * NCHUNK_);
  const float4* s4 = (const float4*)(Sc + (size_t)s * NCHUNK_);
  float4* hi4 = (float4*)(Hin + (size_t)s * NCHUNK_);
  #pragma unroll
  for (int cq = 0; cq < NCHUNK_ / 4; ++cq) {
    const float4 F = f4[cq];
    const float4 S = s4[cq];
    float4 Hv;
    Hv.x = hcur; hcur = fmaf(F.x, hcur, S.x);
    Hv.y = hcur; hcur = fmaf(F.y, hcur, S.y);
    Hv.z = hcur; hcur = fmaf(F.z, hcur, S.z);
    Hv.w = hcur; hcur = fmaf(F.w, hcur, S.w);
    hi4[cq] = Hv;
  }
}

// ---------------------------------------------------------------------------
// Kernel 6: fix-up — rerun chunk recurrence with carried h_in, write out[:,1:,:].
// ---------------------------------------------------------------------------
__global__ void scan_pass3(const unsigned int* __restrict__ AV,
                           const float* __restrict__ Hin, float* __restrict__ out) {
  const int gid = blockIdx.x * 256 + threadIdx.x;
  const int hl = gid & 63;
  const int rest = gid >> 6;
  const int hbi = rest & 7;
  const int c = (rest >> 3) & 63;
  const int b = rest >> 9;
  const unsigned int* p = AV + (size_t)rest * (CHUNK_ * 64) + hl;
  float* o = out + ((size_t)(b * (T_ + 1) + c * CHUNK_ + 1) * H_) + hbi * 64 + hl;
  const int s = b * 512 + hbi * 64 + hl;
  float hcur = Hin[(size_t)s * NCHUNK_ + c];
  #pragma unroll 8
  for (int t = 0; t < CHUNK_; ++t) {
    unsigned int w = p[t * 64];
    float a = bf2f((unsigned short)(w & 0xffffu));
    float v = bf2f((unsigned short)(w >> 16));
    hcur = fmaf(a, hcur, v);
    o[(size_t)t * H_] = hcur;
  }
}

extern "C" void kernel_launch(void* const* d_in, const int* in_sizes, int n_in,
                              void* d_out, int out_size, void* d_ws, size_t ws_size,
                              hipStream_t stream) {
  const float* x  = (const float*)d_in[0];
  const float* h0 = (const float*)d_in[1];
  const float* Wf = (const float*)d_in[2];
  const float* bF = (const float*)d_in[3];
  const float* Wi = (const float*)d_in[4];
  const float* bI = (const float*)d_in[5];
  const float* Wh = (const float*)d_in[6];
  const float* bH = (const float*)d_in[7];
  float* out = (float*)d_out;

  char* ws = (char*)d_ws;
  size_t off = 0;
  unsigned int* AV = (unsigned int*)(ws + off);      off += (size_t)M_ * H_ * 4;        // 64 MB
  unsigned short* xbf = (unsigned short*)(ws + off); off += (size_t)M_ * D_ * 2;        // 32 MB
  unsigned short* Wt = (unsigned short*)(ws + off);  off += (size_t)3 * H_ * D_ * 2;    // 1.5 MB
  float* Fc  = (float*)(ws + off); off += (size_t)NCHUNK_ * SEQS_ * 4;                  // 512 KB
  float* Sc  = (float*)(ws + off); off += (size_t)NCHUNK_ * SEQS_ * 4;                  // 512 KB
  float* Hin = (float*)(ws + off); off += (size_t)NCHUNK_ * SEQS_ * 4;                  // 512 KB

  wt_convert<<<(3 * H_ * D_) / 256, 256, 0, stream>>>(Wf, Wi, Wh, Wt);
  x_convert<<<(M_ * D_) / (256 * 8), 256, 0, stream>>>(x, xbf);
  gemm_gates<<<dim3(H_ / 64, M_ / 128), 256, 0, stream>>>(xbf, Wt, bF, bI, bH, AV);
  scan_pass1<<<(SEQS_ * NCHUNK_) / 256, 256, 0, stream>>>(AV, Fc, Sc);
  scan_pass2<<<SEQS_ / 256, 256, 0, stream>>>(h0, Fc, Sc, Hin, out);
  scan_pass3<<<(SEQS_ * NCHUNK_) / 256, 256, 0, stream>>>(AV, Hin, out);
}